// Round 5
// baseline (395.970 us; speedup 1.0000x reference)
//
#include <hip/hip_runtime.h>
#include <cstddef>

#define DIM 2048
#define NTOK 8192
#define NEUMANN_ITERS 6

// Single fused kernel. Math (validated rounds 1-4):
//   omega = P Q^T, P=[U|V], Q=[sV|-sU], G = Q^T P  (16x16)
//   R = I + P H Q^T, H = 0.5 I + (2I-G)^{-1}(I + 0.5 G)
//   (2I-G)^{-1}(I+0.5G) = 0.5*Y,  Y = (I - G/2)^{-1}(I + 0.5G)
//     -> Horner/Neumann: Y <- B + 0.5*G*Y, B = I + 0.5G   (rho(G)~0.025)
//   H = 0.5*(I + Y)
//   out = x + sum_k c[k] P[:,k],  c[k] = s * sum_j H[k][j] b[j],
//     b[j<8] = av[j], b[j>=8] = -au[j-8];  au = x.U, av = x.V
//     -> c[k] = 0.5*s*( b[k] + sum_j Y[k][j] b[j] )
// Every block computes the 16x16 setup redundantly (~2-3 us, parallel);
// this avoids ANY small-grid dispatch (1-block kernels measured ~100 us
// stall-floor in rounds 2/4 regardless of content). No workspace needed.

__global__ __launch_bounds__(256, 4) void rora_fused(
    const float* __restrict__ x, const float* __restrict__ U,
    const float* __restrict__ V, const float* __restrict__ gate,
    float* __restrict__ out) {
  __shared__ float red[3][64][4];
  __shared__ float prodS[3][64];
  __shared__ float Gs[16][17];
  __shared__ float Bm[16][17];
  __shared__ float Ya[16][17];
  __shared__ float Yb[16][17];

  const int t = threadIdx.x;
  const int wv = t >> 6, lane = t & 63;

  // ---- Gram products: thread = (entry e=(i,j), d-slice), loop q ----
  {
    const int e = t >> 2;      // 0..63
    const int slice = t & 3;   // d in [slice*512, slice*512+512)
    const int i = e >> 3, j = e & 7;
    const int d0 = slice * 512;
    for (int q = 0; q < 3; ++q) {      // 0: U^T U, 1: U^T V, 2: V^T V
      const float* A = (q == 2) ? V : U;
      const float* B = (q == 0) ? U : V;
      float acc = 0.f;
#pragma unroll 8
      for (int dd = 0; dd < 512; ++dd) {
        const int d = d0 + dd;
        acc = fmaf(A[d * 8 + i], B[d * 8 + j], acc);
      }
      red[q][e][slice] = acc;
    }
  }
  __syncthreads();
  if (t < 192) {
    const int q = t >> 6, e = t & 63;
    prodS[q][e] = (red[q][e][0] + red[q][e][1]) + (red[q][e][2] + red[q][e][3]);
  }
  __syncthreads();

  const float sg = 1.f / (1.f + expf(-gate[0]));

  // ---- assemble G, B = I + 0.5G; init Y = B ----
  {
    const int r = t >> 4, c = t & 15;
    float g;
    if (r < 8) g = (c < 8) ? sg * prodS[1][c * 8 + r]              // (V^T U)
                           : sg * prodS[2][r * 8 + (c - 8)];       // (V^T V)
    else       g = (c < 8) ? -sg * prodS[0][(r - 8) * 8 + c]       // -(U^T U)
                           : -sg * prodS[1][(r - 8) * 8 + (c - 8)];
    const float b = ((r == c) ? 1.f : 0.f) + 0.5f * g;
    Gs[r][c] = g;
    Bm[r][c] = b;
    Ya[r][c] = b;
  }
  __syncthreads();

  // ---- Neumann-Horner: Y <- B + 0.5*G*Y (6 iters, ends in Ya) ----
  {
    const int r = t >> 4, c = t & 15;
#pragma unroll
    for (int m = 0; m < NEUMANN_ITERS; ++m) {
      const float (*Yp)[17] = (m & 1) ? Yb : Ya;
      float (*Yn)[17] = (m & 1) ? Ya : Yb;
      float acc = Bm[r][c];
#pragma unroll
      for (int j = 0; j < 16; ++j)
        acc = fmaf(0.5f * Gs[r][j], Yp[j][c], acc);
      Yn[r][c] = acc;          // Yn != Yp: no intra-iter hazard
      __syncthreads();
    }
  }

  // ---- phase 1: a = [x.U | x.V] for this wave's 2 rows ----
  const int row0 = blockIdx.x * 8 + wv * 2;
  const float* xr0 = x + (size_t)row0 * DIM;
  const float* xr1 = xr0 + DIM;
  const float4* U4 = (const float4*)U;
  const float4* V4 = (const float4*)V;

  float a0[16], a1[16];
#pragma unroll
  for (int k = 0; k < 16; ++k) { a0[k] = 0.f; a1[k] = 0.f; }

#pragma unroll 2
  for (int i = 0; i < 32; ++i) {
    const int d = i * 64 + lane;
    const float4 ua = U4[2 * d], ub = U4[2 * d + 1];
    const float4 va = V4[2 * d], vb = V4[2 * d + 1];
    const float x0 = xr0[d], x1 = xr1[d];
    a0[0] = fmaf(x0, ua.x, a0[0]);   a1[0] = fmaf(x1, ua.x, a1[0]);
    a0[1] = fmaf(x0, ua.y, a0[1]);   a1[1] = fmaf(x1, ua.y, a1[1]);
    a0[2] = fmaf(x0, ua.z, a0[2]);   a1[2] = fmaf(x1, ua.z, a1[2]);
    a0[3] = fmaf(x0, ua.w, a0[3]);   a1[3] = fmaf(x1, ua.w, a1[3]);
    a0[4] = fmaf(x0, ub.x, a0[4]);   a1[4] = fmaf(x1, ub.x, a1[4]);
    a0[5] = fmaf(x0, ub.y, a0[5]);   a1[5] = fmaf(x1, ub.y, a1[5]);
    a0[6] = fmaf(x0, ub.z, a0[6]);   a1[6] = fmaf(x1, ub.z, a1[6]);
    a0[7] = fmaf(x0, ub.w, a0[7]);   a1[7] = fmaf(x1, ub.w, a1[7]);
    a0[8]  = fmaf(x0, va.x, a0[8]);  a1[8]  = fmaf(x1, va.x, a1[8]);
    a0[9]  = fmaf(x0, va.y, a0[9]);  a1[9]  = fmaf(x1, va.y, a1[9]);
    a0[10] = fmaf(x0, va.z, a0[10]); a1[10] = fmaf(x1, va.z, a1[10]);
    a0[11] = fmaf(x0, va.w, a0[11]); a1[11] = fmaf(x1, va.w, a1[11]);
    a0[12] = fmaf(x0, vb.x, a0[12]); a1[12] = fmaf(x1, vb.x, a1[12]);
    a0[13] = fmaf(x0, vb.y, a0[13]); a1[13] = fmaf(x1, vb.y, a1[13]);
    a0[14] = fmaf(x0, vb.z, a0[14]); a1[14] = fmaf(x1, vb.z, a1[14]);
    a0[15] = fmaf(x0, vb.w, a0[15]); a1[15] = fmaf(x1, vb.w, a1[15]);
  }

  // ---- wave butterfly: full-row dots on every lane ----
#pragma unroll
  for (int m = 1; m < 64; m <<= 1)
#pragma unroll
    for (int k = 0; k < 16; ++k) {
      a0[k] += __shfl_xor(a0[k], m, 64);
      a1[k] += __shfl_xor(a1[k], m, 64);
    }

  // ---- c[k] = 0.5*s*( b[k] + sum_j Y[k][j] b[j] ), lane k=lane&15 ----
  const int kk = lane & 15;
  float yrow[16];
#pragma unroll
  for (int j = 0; j < 16; ++j) yrow[j] = Ya[kk][j];
  const float bk0 = (kk < 8) ? a0[8 + kk] : -a0[kk - 8];
  const float bk1 = (kk < 8) ? a1[8 + kk] : -a1[kk - 8];
  float s0 = bk0, s1 = bk1;
#pragma unroll
  for (int j = 0; j < 8; ++j) {
    s0 = fmaf(yrow[j], a0[8 + j], s0);  s0 = fmaf(-yrow[8 + j], a0[j], s0);
    s1 = fmaf(yrow[j], a1[8 + j], s1);  s1 = fmaf(-yrow[8 + j], a1[j], s1);
  }
  const float hs = 0.5f * sg;
  const float cp0 = hs * s0, cp1 = hs * s1;

  float c0[16], c1[16];
#pragma unroll
  for (int k = 0; k < 16; ++k) {
    c0[k] = __shfl(cp0, k, 64);   // lane k holds kk==k
    c1[k] = __shfl(cp1, k, 64);
  }

  // ---- phase 2: out = x + sum_{k<8} c[k]*U[:,k] + c[8+k]*V[:,k] ----
  float* o0 = out + (size_t)row0 * DIM;
  float* o1 = o0 + DIM;
#pragma unroll 2
  for (int i = 0; i < 32; ++i) {
    const int d = i * 64 + lane;
    const float4 ua = U4[2 * d], ub = U4[2 * d + 1];
    const float4 va = V4[2 * d], vb = V4[2 * d + 1];
    float r0 = xr0[d], r1 = xr1[d];
    r0 = fmaf(c0[0], ua.x, r0);   r1 = fmaf(c1[0], ua.x, r1);
    r0 = fmaf(c0[1], ua.y, r0);   r1 = fmaf(c1[1], ua.y, r1);
    r0 = fmaf(c0[2], ua.z, r0);   r1 = fmaf(c1[2], ua.z, r1);
    r0 = fmaf(c0[3], ua.w, r0);   r1 = fmaf(c1[3], ua.w, r1);
    r0 = fmaf(c0[4], ub.x, r0);   r1 = fmaf(c1[4], ub.x, r1);
    r0 = fmaf(c0[5], ub.y, r0);   r1 = fmaf(c1[5], ub.y, r1);
    r0 = fmaf(c0[6], ub.z, r0);   r1 = fmaf(c1[6], ub.z, r1);
    r0 = fmaf(c0[7], ub.w, r0);   r1 = fmaf(c1[7], ub.w, r1);
    r0 = fmaf(c0[8],  va.x, r0);  r1 = fmaf(c1[8],  va.x, r1);
    r0 = fmaf(c0[9],  va.y, r0);  r1 = fmaf(c1[9],  va.y, r1);
    r0 = fmaf(c0[10], va.z, r0);  r1 = fmaf(c1[10], va.z, r1);
    r0 = fmaf(c0[11], va.w, r0);  r1 = fmaf(c1[11], va.w, r1);
    r0 = fmaf(c0[12], vb.x, r0);  r1 = fmaf(c1[12], vb.x, r1);
    r0 = fmaf(c0[13], vb.y, r0);  r1 = fmaf(c1[13], vb.y, r1);
    r0 = fmaf(c0[14], vb.z, r0);  r1 = fmaf(c1[14], vb.z, r1);
    r0 = fmaf(c0[15], vb.w, r0);  r1 = fmaf(c1[15], vb.w, r1);
    o0[d] = r0;
    o1[d] = r1;
  }
}

extern "C" void kernel_launch(void* const* d_in, const int* in_sizes, int n_in,
                              void* d_out, int out_size, void* d_ws, size_t ws_size,
                              hipStream_t stream) {
  const float* x    = (const float*)d_in[0];
  const float* U    = (const float*)d_in[1];
  const float* V    = (const float*)d_in[2];
  const float* gate = (const float*)d_in[3];
  float* out = (float*)d_out;

  rora_fused<<<NTOK / 8, 256, 0, stream>>>(x, U, V, gate, out);
}

// Round 6
// 206.345 us; speedup vs baseline: 1.9190x; 1.9190x over previous
//
#include <hip/hip_runtime.h>
#include <cstddef>

#define DIM 2048
#define NTOK 8192
#define NEUMANN_ITERS 6

// Math (validated rounds 1-5):
//   omega = P Q^T, P=[U|V], Q=[sV|-sU], G = Q^T P  (16x16)
//   Y = (I - G/2)^{-1}(I + G/2)  via Neumann-Horner: Y <- B + 0.5*G*Y, B=I+G/2
//   out = x + sum_k c[k] P[:,k],
//   c[k] = 0.5*s*( b[k] + sum_j Y[k][j] b[j] ) = 0.5*s* sum_j Z[k][j] b[j],
//     Z = I + Y,  b[j<8] = av[j], b[j>=8] = -au[j-8];  au = x.U, av = x.V
//
// Structural lessons baked in:
//  - No 1-block dispatches (rounds 2/4: ~100 us stall floor each).
//  - No per-block redundant gram loop (round 5: uncoalesced scalar loads,
//    ~380 us). Gram runs once, wide (192 blocks); fused preamble only loads
//    192 floats + 16x16 Neumann (~2 us).
//  - No runtime indexing of register arrays (scratch trap): b[kk] folded
//    into Z so all per-register indices are compile-time.
//  - ws usage: 192 floats (round 3 showed large ws overruns corrupt state).

// ---------------------------------------------------------------------------
// 1) Gram: one block per entry e=(q,i,j); 256 threads reduce over d=2048.
// ---------------------------------------------------------------------------
__global__ __launch_bounds__(256) void rora_gram(
    const float* __restrict__ U, const float* __restrict__ V,
    float* __restrict__ prod) {
  const int e = blockIdx.x;            // 0..191
  const int q = e >> 6;                // 0: U^T U, 1: U^T V, 2: V^T V
  const int i = (e >> 3) & 7, j = e & 7;
  const float* A = (q == 2) ? V : U;
  const float* B = (q == 0) ? U : V;
  const int t = threadIdx.x;
  float acc = 0.f;
#pragma unroll
  for (int s = 0; s < 8; ++s) {
    const int d = s * 256 + t;
    acc = fmaf(A[d * 8 + i], B[d * 8 + j], acc);
  }
#pragma unroll
  for (int m = 1; m < 64; m <<= 1) acc += __shfl_xor(acc, m, 64);
  __shared__ float wsum[4];
  if ((t & 63) == 0) wsum[t >> 6] = acc;
  __syncthreads();
  if (t == 0) prod[e] = (wsum[0] + wsum[1]) + (wsum[2] + wsum[3]);
}

// ---------------------------------------------------------------------------
// 2) Fused: cheap per-block 16x16 setup + streaming main, 4 rows/wave.
// ---------------------------------------------------------------------------
__global__ __launch_bounds__(256, 4) void rora_fused(
    const float* __restrict__ x, const float* __restrict__ U,
    const float* __restrict__ V, const float* __restrict__ gate,
    const float* __restrict__ prod, float* __restrict__ out) {
  __shared__ float prodS[192];     // [q*64 + i*8 + j]
  __shared__ float Gs[16][17];
  __shared__ float Bm[16][17];
  __shared__ float Ya[16][17];
  __shared__ float Yb[16][17];
  const int t = threadIdx.x;

  if (t < 192) prodS[t] = prod[t];
  __syncthreads();
  const float sg = 1.f / (1.f + expf(-gate[0]));
  {
    const int r = t >> 4, c = t & 15;
    float g;
    if (r < 8) g = (c < 8) ? sg * prodS[64 + c * 8 + r]              // (V^T U)
                           : sg * prodS[128 + r * 8 + (c - 8)];      // (V^T V)
    else       g = (c < 8) ? -sg * prodS[(r - 8) * 8 + c]            // -(U^T U)
                           : -sg * prodS[64 + (r - 8) * 8 + (c - 8)];
    const float b = ((r == c) ? 1.f : 0.f) + 0.5f * g;
    Gs[r][c] = g;
    Bm[r][c] = b;
    Ya[r][c] = b;
  }
  __syncthreads();
  {
    const int r = t >> 4, c = t & 15;
#pragma unroll
    for (int m = 0; m < NEUMANN_ITERS; ++m) {   // ends in Ya (m=5 odd)
      const float (*Yp)[17] = (m & 1) ? Yb : Ya;
      float (*Yn)[17] = (m & 1) ? Ya : Yb;
      float acc = Bm[r][c];
#pragma unroll
      for (int j = 0; j < 16; ++j)
        acc = fmaf(0.5f * Gs[r][j], Yp[j][c], acc);
      Yn[r][c] = acc;
      __syncthreads();
    }
  }

  // ---- main: 4 rows per wave ----
  const int wv = t >> 6, lane = t & 63;
  const int row0 = blockIdx.x * 16 + wv * 4;
  const float* xr = x + (size_t)row0 * DIM;
  float* orow = out + (size_t)row0 * DIM;
  const float4* U4 = (const float4*)U;
  const float4* V4 = (const float4*)V;

  float a[4][16];
#pragma unroll
  for (int r = 0; r < 4; ++r)
#pragma unroll
    for (int k = 0; k < 16; ++k) a[r][k] = 0.f;

  // phase 1: a[r] = [x_r.U | x_r.V] partials (lane owns d = i*64+lane)
#pragma unroll 2
  for (int i = 0; i < 32; ++i) {
    const int d = i * 64 + lane;
    const float4 ua = U4[2 * d], ub = U4[2 * d + 1];
    const float4 va = V4[2 * d], vb = V4[2 * d + 1];
    const float uu[16] = {ua.x, ua.y, ua.z, ua.w, ub.x, ub.y, ub.z, ub.w,
                          va.x, va.y, va.z, va.w, vb.x, vb.y, vb.z, vb.w};
    float xv[4];
#pragma unroll
    for (int r = 0; r < 4; ++r) xv[r] = xr[(size_t)r * DIM + d];
#pragma unroll
    for (int r = 0; r < 4; ++r) {
      const float xi = xv[r];
#pragma unroll
      for (int k = 0; k < 16; ++k) a[r][k] = fmaf(xi, uu[k], a[r][k]);
    }
  }

  // wave butterfly: full-row dots on every lane
#pragma unroll
  for (int m = 1; m < 64; m <<= 1)
#pragma unroll
    for (int r = 0; r < 4; ++r)
#pragma unroll
      for (int k = 0; k < 16; ++k) a[r][k] += __shfl_xor(a[r][k], m, 64);

  // c[k] = 0.5*s * sum_j Z[k][j] b[j]; lane kk=lane&15 computes row kk.
  // Z-row fetched from LDS (runtime kk OK); register indices compile-time.
  {
    const int kk = lane & 15;
    float zrow[16];
#pragma unroll
    for (int j = 0; j < 16; ++j)
      zrow[j] = Ya[kk][j] + ((j == kk) ? 1.f : 0.f);
    const float hs = 0.5f * sg;
    float cp[4];
#pragma unroll
    for (int r = 0; r < 4; ++r) {
      float s = 0.f;
#pragma unroll
      for (int j = 0; j < 8; ++j) {
        s = fmaf(zrow[j], a[r][8 + j], s);     //  Y[k][j]   * av[j]
        s = fmaf(-zrow[8 + j], a[r][j], s);    // -Y[k][8+j] * au[j]
      }
      cp[r] = hs * s;
    }
#pragma unroll
    for (int r = 0; r < 4; ++r)
#pragma unroll
      for (int k = 0; k < 16; ++k) a[r][k] = __shfl(cp[r], k, 64);
  }

  // phase 2: out[r][d] = x[r][d] + sum_{k<8} c[k]*U[d][k] + c[8+k]*V[d][k]
#pragma unroll 2
  for (int i = 0; i < 32; ++i) {
    const int d = i * 64 + lane;
    const float4 ua = U4[2 * d], ub = U4[2 * d + 1];
    const float4 va = V4[2 * d], vb = V4[2 * d + 1];
    const float uu[16] = {ua.x, ua.y, ua.z, ua.w, ub.x, ub.y, ub.z, ub.w,
                          va.x, va.y, va.z, va.w, vb.x, vb.y, vb.z, vb.w};
#pragma unroll
    for (int r = 0; r < 4; ++r) {
      float acc = xr[(size_t)r * DIM + d];
#pragma unroll
      for (int k = 0; k < 16; ++k) acc = fmaf(a[r][k], uu[k], acc);
      orow[(size_t)r * DIM + d] = acc;
    }
  }
}

extern "C" void kernel_launch(void* const* d_in, const int* in_sizes, int n_in,
                              void* d_out, int out_size, void* d_ws, size_t ws_size,
                              hipStream_t stream) {
  const float* x    = (const float*)d_in[0];
  const float* U    = (const float*)d_in[1];
  const float* V    = (const float*)d_in[2];
  const float* gate = (const float*)d_in[3];
  float* out = (float*)d_out;
  float* prodw = (float*)d_ws;   // 192 floats

  rora_gram<<<192, 256, 0, stream>>>(U, V, prodw);
  rora_fused<<<NTOK / 16, 256, 0, stream>>>(x, U, V, gate, prodw, out);
}

// Round 7
// 63.601 us; speedup vs baseline: 6.2258x; 3.2444x over previous
//
#include <hip/hip_runtime.h>
#include <cstddef>

#define DIM 2048
#define NTOK 8192
#define NEUMANN_ITERS 6

// Math (validated rounds 1-6):
//   omega = P Q^T, P=[U|V], Q=[sV|-sU], G = Q^T P  (16x16)
//   Y = (I - G/2)^{-1}(I + G/2)  via Neumann-Horner: Y <- B + 0.5*G*Y, B=I+G/2
//   out = x + sum_k c[k] P[:,k],
//   c[k] = 0.5*s* sum_j Z[k][j] b[j],  Z = I + Y,
//     b[j<8] = av[j], b[j>=8] = -au[j-8];  au = x.U, av = x.V
//
// Structural lessons baked in:
//  - No 1-block dispatches (rounds 2/4: ~100 us stall floor each).
//  - No per-block redundant gram loop (round 5: ~380 us uncoalesced preamble).
//  - NO min-waves clause in launch_bounds (round 6: ",4" capped VGPR at 64 ->
//    a[4][16] spilled to scratch, +72 MB each way, 221 us). Let the
//    allocator size registers; a[4][16]+temps needs ~110-160 VGPR.
//  - No runtime indexing of register arrays (scratch trap).
//  - ws usage: 192 floats only.

// ---------------------------------------------------------------------------
// 1) Gram: one block per entry e=(q,i,j); 256 threads reduce over d=2048.
// ---------------------------------------------------------------------------
__global__ __launch_bounds__(256) void rora_gram(
    const float* __restrict__ U, const float* __restrict__ V,
    float* __restrict__ prod) {
  const int e = blockIdx.x;            // 0..191
  const int q = e >> 6;                // 0: U^T U, 1: U^T V, 2: V^T V
  const int i = (e >> 3) & 7, j = e & 7;
  const float* A = (q == 2) ? V : U;
  const float* B = (q == 0) ? U : V;
  const int t = threadIdx.x;
  float acc = 0.f;
#pragma unroll
  for (int s = 0; s < 8; ++s) {
    const int d = s * 256 + t;
    acc = fmaf(A[d * 8 + i], B[d * 8 + j], acc);
  }
#pragma unroll
  for (int m = 1; m < 64; m <<= 1) acc += __shfl_xor(acc, m, 64);
  __shared__ float wsum[4];
  if ((t & 63) == 0) wsum[t >> 6] = acc;
  __syncthreads();
  if (t == 0) prod[e] = (wsum[0] + wsum[1]) + (wsum[2] + wsum[3]);
}

// ---------------------------------------------------------------------------
// 2) Fused: cheap per-block 16x16 setup + streaming main, 4 rows/wave.
// ---------------------------------------------------------------------------
__global__ __launch_bounds__(256) void rora_fused(
    const float* __restrict__ x, const float* __restrict__ U,
    const float* __restrict__ V, const float* __restrict__ gate,
    const float* __restrict__ prod, float* __restrict__ out) {
  __shared__ float prodS[192];     // [q*64 + i*8 + j]
  __shared__ float Gs[16][17];
  __shared__ float Bm[16][17];
  __shared__ float Ya[16][17];
  __shared__ float Yb[16][17];
  const int t = threadIdx.x;

  if (t < 192) prodS[t] = prod[t];
  __syncthreads();
  const float sg = 1.f / (1.f + expf(-gate[0]));
  {
    const int r = t >> 4, c = t & 15;
    float g;
    if (r < 8) g = (c < 8) ? sg * prodS[64 + c * 8 + r]              // (V^T U)
                           : sg * prodS[128 + r * 8 + (c - 8)];      // (V^T V)
    else       g = (c < 8) ? -sg * prodS[(r - 8) * 8 + c]            // -(U^T U)
                           : -sg * prodS[64 + (r - 8) * 8 + (c - 8)];
    const float b = ((r == c) ? 1.f : 0.f) + 0.5f * g;
    Gs[r][c] = g;
    Bm[r][c] = b;
    Ya[r][c] = b;
  }
  __syncthreads();
  {
    const int r = t >> 4, c = t & 15;
#pragma unroll
    for (int m = 0; m < NEUMANN_ITERS; ++m) {   // ends in Ya (last m odd)
      const float (*Yp)[17] = (m & 1) ? Yb : Ya;
      float (*Yn)[17] = (m & 1) ? Ya : Yb;
      float acc = Bm[r][c];
#pragma unroll
      for (int j = 0; j < 16; ++j)
        acc = fmaf(0.5f * Gs[r][j], Yp[j][c], acc);
      Yn[r][c] = acc;
      __syncthreads();
    }
  }

  // ---- main: 4 rows per wave ----
  const int wv = t >> 6, lane = t & 63;
  const int row0 = blockIdx.x * 16 + wv * 4;
  const float* xr = x + (size_t)row0 * DIM;
  float* orow = out + (size_t)row0 * DIM;
  const float4* U4 = (const float4*)U;
  const float4* V4 = (const float4*)V;

  float a[4][16];
#pragma unroll
  for (int r = 0; r < 4; ++r)
#pragma unroll
    for (int k = 0; k < 16; ++k) a[r][k] = 0.f;

  // phase 1: a[r] = [x_r.U | x_r.V] partials (lane owns d = i*64+lane)
#pragma unroll 2
  for (int i = 0; i < 32; ++i) {
    const int d = i * 64 + lane;
    const float4 ua = U4[2 * d], ub = U4[2 * d + 1];
    const float4 va = V4[2 * d], vb = V4[2 * d + 1];
    const float uu[16] = {ua.x, ua.y, ua.z, ua.w, ub.x, ub.y, ub.z, ub.w,
                          va.x, va.y, va.z, va.w, vb.x, vb.y, vb.z, vb.w};
    float xv[4];
#pragma unroll
    for (int r = 0; r < 4; ++r) xv[r] = xr[(size_t)r * DIM + d];
#pragma unroll
    for (int r = 0; r < 4; ++r) {
      const float xi = xv[r];
#pragma unroll
      for (int k = 0; k < 16; ++k) a[r][k] = fmaf(xi, uu[k], a[r][k]);
    }
  }

  // wave butterfly: full-row dots on every lane
#pragma unroll
  for (int m = 1; m < 64; m <<= 1)
#pragma unroll
    for (int r = 0; r < 4; ++r)
#pragma unroll
      for (int k = 0; k < 16; ++k) a[r][k] += __shfl_xor(a[r][k], m, 64);

  // c[k] = 0.5*s * sum_j Z[k][j] b[j]; lane kk=lane&15 computes row kk.
  {
    const int kk = lane & 15;
    float zrow[16];
#pragma unroll
    for (int j = 0; j < 16; ++j)
      zrow[j] = Ya[kk][j] + ((j == kk) ? 1.f : 0.f);
    const float hs = 0.5f * sg;
    float cp[4];
#pragma unroll
    for (int r = 0; r < 4; ++r) {
      float s = 0.f;
#pragma unroll
      for (int j = 0; j < 8; ++j) {
        s = fmaf(zrow[j], a[r][8 + j], s);     //  Z[k][j]   * av[j]
        s = fmaf(-zrow[8 + j], a[r][j], s);    // -Z[k][8+j] * au[j]
      }
      cp[r] = hs * s;
    }
#pragma unroll
    for (int r = 0; r < 4; ++r)
#pragma unroll
      for (int k = 0; k < 16; ++k) a[r][k] = __shfl(cp[r], k, 64);
  }

  // phase 2: out[r][d] = x[r][d] + sum_{k<8} c[k]*U[d][k] + c[8+k]*V[d][k]
#pragma unroll 2
  for (int i = 0; i < 32; ++i) {
    const int d = i * 64 + lane;
    const float4 ua = U4[2 * d], ub = U4[2 * d + 1];
    const float4 va = V4[2 * d], vb = V4[2 * d + 1];
    const float uu[16] = {ua.x, ua.y, ua.z, ua.w, ub.x, ub.y, ub.z, ub.w,
                          va.x, va.y, va.z, va.w, vb.x, vb.y, vb.z, vb.w};
#pragma unroll
    for (int r = 0; r < 4; ++r) {
      float acc = xr[(size_t)r * DIM + d];
#pragma unroll
      for (int k = 0; k < 16; ++k) acc = fmaf(a[r][k], uu[k], acc);
      orow[(size_t)r * DIM + d] = acc;
    }
  }
}

extern "C" void kernel_launch(void* const* d_in, const int* in_sizes, int n_in,
                              void* d_out, int out_size, void* d_ws, size_t ws_size,
                              hipStream_t stream) {
  const float* x    = (const float*)d_in[0];
  const float* U    = (const float*)d_in[1];
  const float* V    = (const float*)d_in[2];
  const float* gate = (const float*)d_in[3];
  float* out = (float*)d_out;
  float* prodw = (float*)d_ws;   // 192 floats

  rora_gram<<<192, 256, 0, stream>>>(U, V, prodw);
  rora_fused<<<NTOK / 16, 256, 0, stream>>>(x, U, V, gate, prodw, out);
}